// Round 8
// baseline (100.624 us; speedup 1.0000x reference)
//
#include <hip/hip_runtime.h>
#include <math.h>

#define BATCH 16
#define NCLS 80
#define SUMHW 7581            // 76*76 + 38*38 + 19*19
#define NN 22743              // 3 anchors * SUMHW
#define ASTRIDE 7584          // padded per-anchor stride for so/xthr (7581 -> 7584, /4)
#define PADNN (3 * ASTRIDE)   // 22752
#define TOPK 128
#define CAP 1024              // fallback gather cap
#define GCAP 2048             // per-(b,c) candidate list capacity (mean ~670)
#define STAGECAP 96           // per-class LDS staging cap in scatter
#define PRUNECAP 512          // post-prune survivor cap in select
#define CG 16                 // classes per scatter group (5 groups x 16 = 80)
#define KEYBASE 0x3E800000u   // bits of 0.25f (fallback histogram base)
#define KB2     0x3F180000u   // bits of 0.59375f (prune histogram base)
#define SBITS   0x3F19999Au   // bits of 0.6f

// exact sigmoid matching numpy f32 chain: correctly-rounded exp (double) -> f32 ops
__device__ __forceinline__ float sigf(float x) {
    float e = (float)exp(-(double)x);
    return 1.0f / (1.0f + e);
}
__device__ __forceinline__ float expf_cr(float x) {
    return (float)exp((double)x);
}

struct DecParams { float aw[9]; float ah[9]; };

// ---------------- Stage A: exact objectness + x-threshold (obj channel only) ----------------
// xthr correctness (r5-r7 validated):
//   Tp = 0.59999 (< 0.6f).  thr = -log(so/Tp - 1)  =>  sigmoid(thr) = Tp/so.
//   ex >= 0.6f  =>  x > thr (captured).   x <= thr  =>  ex < 0.6f (safe to miss).
//   so <= 0.59999f  =>  ex < 0.6f  =>  xthr=+INF.
__global__ __launch_bounds__(256) void decode_kernel(
        const float* __restrict__ p0, const float* __restrict__ p1,
        const float* __restrict__ p2,
        float* __restrict__ so_arr, float* __restrict__ xthr_arr) {
    int blk = blockIdx.x;
    int b = blk / 93;
    int rem = blk % 93;
    int a = rem / 31;
    int seg = rem % 31;
    int s, cellblk;
    if (seg < 23)      { s = 0; cellblk = seg; }
    else if (seg < 29) { s = 1; cellblk = seg - 23; }
    else               { s = 2; cellblk = seg - 29; }
    const int HW_[3]  = {5776, 1444, 361};
    const int OFF_[3] = {0, 5776, 7220};
    const float* __restrict__ pr = (s == 0) ? p0 : (s == 1) ? p1 : p2;
    int HW = HW_[s];
    int cell = cellblk * 256 + (int)threadIdx.x;
    if (cell >= HW) return;
    float obj = pr[((size_t)b * 255 + (size_t)a * 85 + 4) * (size_t)HW + cell];
    float so = sigf(obj);
    size_t pidx = (size_t)b * PADNN + a * ASTRIDE + OFF_[s] + cell;
    so_arr[pidx] = so;
    float thr = __int_as_float(0x7F800000);       // +INF
    if (so > 0.59999f) {
        double arg = (double)so / 0.59999 - 1.0;
        thr = __double2float_rd(-log(arg));       // round DOWN: conservative capture
    }
    xthr_arr[pidx] = thr;
}

// ---------------- Stage B: dense stream, branchless mask, bitmask drain ----------------
// grid: 16 b * 3 a * 9 cellsegs(6 s0 + 2 s1 + 1 s2) * 5 classgroups = 2160 blocks
__global__ __launch_bounds__(256) void scatter_kernel(
        const float* __restrict__ p0, const float* __restrict__ p1,
        const float* __restrict__ p2,
        const float* __restrict__ xthr_arr,
        unsigned int* __restrict__ nlist, unsigned int* __restrict__ gcnt) {
    __shared__ unsigned int svals[CG][STAGECAP];   // 6144 B
    __shared__ unsigned int lcnt[CG];
    __shared__ unsigned int lbase[CG];

    int blk = blockIdx.x;
    int b = blk / 135;
    int rem = blk % 135;
    int a = rem / 45;
    int rem2 = rem % 45;
    int seg = rem2 / 5;
    int cg  = rem2 % 5;
    int s, segi;
    if (seg < 6)      { s = 0; segi = seg; }
    else if (seg < 8) { s = 1; segi = seg - 6; }
    else              { s = 2; segi = 0; }
    const int HW_[3]  = {5776, 1444, 361};
    const int OFF_[3] = {0, 5776, 7220};
    const float* __restrict__ pr = (s == 0) ? p0 : (s == 1) ? p1 : p2;
    int HW = HW_[s], OFF = OFF_[s];
    int t = threadIdx.x;

    if (t < CG) lcnt[t] = 0;
    __syncthreads();

    int cell0 = segi * 1024 + t * 4;
    const float INF = __int_as_float(0x7F800000);
    float th0 = INF, th1 = INF, th2 = INF, th3 = INF;
    const float* xt = xthr_arr + (size_t)b * PADNN + a * ASTRIDE + OFF;
    bool vec4 = (s != 2) && (cell0 + 3 < HW);     // s0/s1 active threads are 4-aligned
    if (vec4) {
        float4 tv = *(const float4*)(xt + cell0);
        th0 = tv.x; th1 = tv.y; th2 = tv.z; th3 = tv.w;
    } else if (cell0 < HW) {
        th0 = xt[cell0];
        if (cell0 + 1 < HW) th1 = xt[cell0 + 1];
        if (cell0 + 2 < HW) th2 = xt[cell0 + 2];
        if (cell0 + 3 < HW) th3 = xt[cell0 + 3];
    }
    int n0 = a * SUMHW + OFF + cell0;
    int cbase = cg * CG;
    int rowb = b * NCLS + cbase;
    const float* __restrict__ cp0 =
        pr + ((size_t)b * 255 + (size_t)a * 85 + 5 + (size_t)cbase) * (size_t)HW;

    // --- branchless compare phase: 16 independent float4 loads -> 64-bit mask ---
    unsigned long long mask = 0ULL;
    if (vec4) {
#pragma unroll
        for (int g = 0; g < CG; ++g) {
            float4 xv = *(const float4*)(cp0 + (size_t)g * HW + cell0);
            unsigned mg = (unsigned)(xv.x > th0) | ((unsigned)(xv.y > th1) << 1) |
                          ((unsigned)(xv.z > th2) << 2) | ((unsigned)(xv.w > th3) << 3);
            mask |= (unsigned long long)mg << (g * 4);
        }
    } else if (cell0 < HW) {                      // s2 tail (361 cells)
#pragma unroll
        for (int g = 0; g < CG; ++g) {
            const float* cp = cp0 + (size_t)g * HW;
            unsigned mg = (unsigned)(cp[cell0] > th0);
            if (cell0 + 1 < HW) mg |= (unsigned)(cp[cell0 + 1] > th1) << 1;
            if (cell0 + 2 < HW) mg |= (unsigned)(cp[cell0 + 2] > th2) << 2;
            if (cell0 + 3 < HW) mg |= (unsigned)(cp[cell0 + 3] > th3) << 3;
            mask |= (unsigned long long)mg << (g * 4);
        }
    }

    // --- drain: one (class,cell) per active lane per iteration;
    //     lanes target different lcnt[g] -> parallel-bank LDS atomics (~8 iters/wave) ---
    while (__ballot(mask != 0ULL)) {
        if (mask) {
            int k = __ffsll((unsigned long long)mask) - 1;
            mask &= mask - 1;
            int g = k >> 2, j = k & 3;
            unsigned pos = atomicAdd(&lcnt[g], 1u);
            if (pos < STAGECAP) svals[g][pos] = (unsigned)(n0 + j);
            else {                                 // ~never: direct global spill
                unsigned gp = atomicAdd(&gcnt[rowb + g], 1u);
                if (gp < GCAP) nlist[(size_t)(rowb + g) * GCAP + gp] = (unsigned)(n0 + j);
            }
        }
    }
    __syncthreads();

    // flush: ONE global atomic per class, then coalesced copy
    if (t < CG) {
        unsigned m = lcnt[t]; if (m > STAGECAP) m = STAGECAP;
        lbase[t] = atomicAdd(&gcnt[rowb + t], m);
        lcnt[t] = m;
    }
    __syncthreads();
#pragma unroll 1
    for (int g = 0; g < CG; ++g) {
        unsigned m = lcnt[g], base = lbase[g];
        for (unsigned i = t; i < m; i += 256) {
            unsigned p = base + i;
            if (p < GCAP) nlist[(size_t)(rowb + g) * GCAP + p] = svals[g][i];
        }
    }
}

// ------- Stage C: per-(b,c) key-build + prune + exact rescore + rank-select +
//         lazy box decode + bitmask NMS -------
__global__ __launch_bounds__(256) void select_nms_kernel(
        const float* __restrict__ p0, const float* __restrict__ p1,
        const float* __restrict__ p2,
        const float* __restrict__ so_arr,
        const unsigned int* __restrict__ nlist,
        const unsigned int* __restrict__ gcnt,
        DecParams dp,
        float* __restrict__ out) {
    __shared__ unsigned int kbuf[GCAP];           // 8 KB approx keys
    __shared__ float xbuf[GCAP];                  // 8 KB raw x
    __shared__ unsigned long long skey[CAP];      // 8 KB (fallback needs 1024)
    __shared__ unsigned long long sorted[TOPK];
    __shared__ unsigned long long msk[TOPK][2];
    __shared__ unsigned long long aliveLDS[2];
    __shared__ unsigned int hist[512];
    __shared__ unsigned int sums[256];
    __shared__ float4 bxs4[TOPK];
    __shared__ float pvs[TOPK];
    __shared__ unsigned int sh_bin, sh_above, gcount;

    int t = threadIdx.x;
    int bid = blockIdx.x;          // b*80 + c
    int b = bid / NCLS;
    int c = bid % NCLS;

    // all-pairs rank selection: keys unique (low bits carry ~n) => rank is a permutation
    auto rankSelect = [&](unsigned Gc) {
        if (t < TOPK) sorted[t] = 0ULL;
        __syncthreads();
        unsigned i0 = t, i1 = t + 256, i2 = t + 512, i3 = t + 768;
        bool v0 = i0 < Gc, v1 = i1 < Gc, v2 = i2 < Gc, v3 = i3 < Gc;
        unsigned long long o0 = v0 ? skey[i0] : 0ULL;
        unsigned long long o1 = v1 ? skey[i1] : 0ULL;
        unsigned long long o2 = v2 ? skey[i2] : 0ULL;
        unsigned long long o3 = v3 ? skey[i3] : 0ULL;
        unsigned r0 = 0, r1 = 0, r2 = 0, r3 = 0;
        for (unsigned j = 0; j < Gc; ++j) {
            unsigned long long kj = skey[j];      // wave-uniform addr -> LDS broadcast
            r0 += (kj > o0); r1 += (kj > o1); r2 += (kj > o2); r3 += (kj > o3);
        }
        if (v0 && r0 < TOPK) sorted[r0] = o0;
        if (v1 && r1 < TOPK) sorted[r1] = o1;
        if (v2 && r2 < TOPK) sorted[r2] = o2;
        if (v3 && r3 < TOPK) sorted[r3] = o3;
        __syncthreads();
    };

    unsigned G = gcnt[bid];
    // G < TOPK => true top-128 needs sub-0.6 elements the scatter never captured
    bool fb = (G > GCAP) || (G < TOPK);
    if (!fb) {
        const unsigned int* nl = nlist + (size_t)bid * GCAP;
        for (int i = t; i < 512; i += 256) hist[i] = 0;
        if (t == 0) gcount = 0;
        __syncthreads();
        // --- pass 1: gather x/so, compute approx key (single site => margin proof
        //     self-consistent), stash in LDS, histogram (16384-ulp bins) ---
        for (unsigned i = t; i < G; i += 256) {
            unsigned n = nl[i];
            unsigned a = n / SUMHW;
            unsigned r = n - a * SUMHW;
            size_t cb = (size_t)b * 255 + (size_t)a * 85 + 5 + (size_t)c;
            float x;
            if (r < 5776u)      x = p0[cb * 5776 + r];
            else if (r < 7220u) x = p1[cb * 1444 + (r - 5776u)];
            else                x = p2[cb * 361  + (r - 7220u)];
            float so = so_arr[(size_t)b * PADNN + a * ASTRIDE + r];
            float st = 1.0f / (1.0f + __expf(-x));   // approx sigmoid, err few ulp
            unsigned key = __float_as_uint(st * so); // captured elems ~>=0.59999 > KB2
            kbuf[i] = key; xbuf[i] = x;
            unsigned bin = (key - KB2) >> 14;
            if (bin > 511u) bin = 511u;
            atomicAdd(&hist[bin], 1u);
        }
        __syncthreads();
        unsigned m0 = hist[2 * t], m1 = hist[2 * t + 1];
        sums[t] = m0 + m1;
        __syncthreads();
        for (int d = 1; d < 256; d <<= 1) {
            unsigned v = sums[t];
            if (t + d < 256) v += sums[t + d];
            __syncthreads();
            sums[t] = v;
            __syncthreads();
        }
        unsigned si = sums[t], se = si - (m0 + m1);
        if (se < TOPK && TOPK <= si) {              // unique crossing thread
            if (TOPK <= se + m1) { sh_bin = 2 * t + 1; sh_above = se; }
            else                 { sh_bin = 2 * t;     sh_above = se + m1; }
        }
        __syncthreads();
        unsigned B1 = sh_bin, above1 = sh_above;
        unsigned cntB = hist[B1];
        unsigned binlo = KB2 + (B1 << 14);
        if (above1 + cntB > PRUNECAP - 64) {
            fb = true;                               // fat bin (~never): full re-scan
        } else {
            // --- pass 2: keep keys >= binlo - 256ulp (r3-validated margin);
            //             exact-rescore survivors only ---
            unsigned gth = binlo - 256;
            for (unsigned i = t; i < G; i += 256) {
                if (kbuf[i] >= gth) {
                    unsigned pos = atomicAdd(&gcount, 1u);
                    if (pos < PRUNECAP) {
                        unsigned n = nl[i];
                        unsigned a = n / SUMHW;
                        unsigned r = n - a * SUMHW;
                        float so = so_arr[(size_t)b * PADNN + a * ASTRIDE + r];
                        float ex = so * sigf(xbuf[i]);   // reference-identical chain
                        skey[pos] = (ex > 0.3f)
                            ? (((unsigned long long)__float_as_uint(ex) << 32) |
                               (unsigned)(~n))
                            : (unsigned long long)(unsigned)(~n);   // unique dead key
                    }
                }
            }
            __syncthreads();
            if (gcount > PRUNECAP) fb = true;        // overflow (~never): full re-scan
            if (!fb) {
                unsigned Gc = gcount;
                rankSelect(Gc);
                // success <=> kept 128th has ex >= 0.6f (every scatter-missed elem < 0.6f)
                bool ok = (Gc >= TOPK) && ((unsigned)(sorted[TOPK - 1] >> 32) >= SBITS);
                if (!ok) fb = true;
            }
        }
    }

    if (fb) {
        // ---- full re-scan fallback (rounds 3/4 validated); never taken on bench data ----
        auto scanScalar = [&](auto&& body) {
#pragma unroll
            for (int s = 0; s < 3; ++s) {
                const float* __restrict__ pr = (s == 0) ? p0 : (s == 1) ? p1 : p2;
                const int HW  = (s == 0) ? 5776 : (s == 1) ? 1444 : 361;
                const int OFF = (s == 0) ? 0 : (s == 1) ? 5776 : 7220;
#pragma unroll
                for (int a = 0; a < 3; ++a) {
                    const float* __restrict__ cp =
                        pr + ((size_t)b * 255 + (size_t)a * 85 + 5 + (size_t)c) * (size_t)HW;
                    const float* __restrict__ sop =
                        so_arr + (size_t)b * PADNN + a * ASTRIDE + OFF;
                    int n0 = a * SUMHW + OFF;
                    for (int i = t; i < HW; i += 256) {
                        float so = sop[i];
                        if (so <= 0.2999f) continue;
                        float x = cp[i];
                        float st = 1.0f / (1.0f + __expf(-x));
                        float sca = st * so;
                        if (sca > 0.2999f) body(sca, x, so, n0 + i);
                    }
                }
            }
        };
        __syncthreads();
        for (int i = t; i < 512; i += 256) hist[i] = 0;
        if (t == 0) gcount = 0;
        __syncthreads();
        scanScalar([&](float sca, float, float, int) {
            unsigned bin = (__float_as_uint(sca) - KEYBASE) >> 15;
            if (bin > 511u) bin = 511u;
            atomicAdd(&hist[bin], 1u);
        });
        __syncthreads();
        unsigned m0 = hist[2 * t], m1 = hist[2 * t + 1];
        sums[t] = m0 + m1;
        __syncthreads();
        for (int d = 1; d < 256; d <<= 1) {
            unsigned v = sums[t];
            if (t + d < 256) v += sums[t + d];
            __syncthreads();
            sums[t] = v;
            __syncthreads();
        }
        unsigned total = sums[0];
        bool gatherAll = (total < TOPK);
        unsigned gth = 0;
        if (!gatherAll) {
            unsigned si = sums[t], se = si - (m0 + m1);
            if (se < TOPK && TOPK <= si) {
                if (TOPK <= se + m1) { sh_bin = 2 * t + 1; sh_above = se; }
                else                 { sh_bin = 2 * t;     sh_above = se + m1; }
            }
            __syncthreads();
            unsigned B1 = sh_bin, above1 = sh_above;
            unsigned cntB = hist[B1];
            unsigned binlo = KEYBASE + (B1 << 15);
            __syncthreads();
            if (above1 + cntB <= 768) {
                gth = binlo - 256;
            } else {
                if (t < 256) hist[t] = 0;
                __syncthreads();
                scanScalar([&](float sca, float, float, int) {
                    unsigned key = __float_as_uint(sca);
                    if (((key - KEYBASE) >> 15) == B1) {
                        unsigned sub = (key - binlo) >> 7;
                        if (sub > 255u) sub = 255u;
                        atomicAdd(&hist[sub], 1u);
                    }
                });
                __syncthreads();
                unsigned R2 = TOPK - above1;
                unsigned sl = hist[t];
                sums[t] = sl;
                __syncthreads();
                for (int d = 1; d < 256; d <<= 1) {
                    unsigned v = sums[t];
                    if (t + d < 256) v += sums[t + d];
                    __syncthreads();
                    sums[t] = v;
                    __syncthreads();
                }
                unsigned si2 = sums[t], se2 = si2 - sl;
                if (se2 < R2 && R2 <= si2) sh_bin = (unsigned)t;
                __syncthreads();
                gth = binlo + (sh_bin << 7) - 256;
            }
        }
        __syncthreads();
        scanScalar([&](float sca, float x, float so, int n) {
            unsigned key = __float_as_uint(sca);
            if (gatherAll || key >= gth) {
                unsigned pos = atomicAdd(&gcount, 1u);
                if (pos < CAP) {
                    float ex = so * sigf(x);
                    skey[pos] = (ex > 0.3f)
                        ? (((unsigned long long)__float_as_uint(ex) << 32) |
                           (unsigned)(~(unsigned)n))
                        : (unsigned long long)(unsigned)(~(unsigned)n);
                }
            }
        });
        __syncthreads();
        unsigned Gc = gcount < CAP ? gcount : CAP;
        rankSelect(Gc);
    }

    // --- extract top-128 + LAZY box decode (reference-identical f32 chain) ---
    if (t < TOPK) {
        unsigned long long e = sorted[t];
        bool vld = (e != 0ULL);
        float sc = __uint_as_float((unsigned)(e >> 32));
        unsigned n = ~(unsigned)(e & 0xFFFFFFFFu);
        float4 bb = make_float4(0.f, 0.f, 0.f, 0.f);
        if (vld) {
            unsigned a = n / SUMHW;
            unsigned r = n - a * SUMHW;
            int s, S, HW, off; const float* pr;
            if (r < 5776u)      { s = 0; S = 76; HW = 5776; off = 0;    pr = p0; }
            else if (r < 7220u) { s = 1; S = 38; HW = 1444; off = 5776; pr = p1; }
            else                { s = 2; S = 19; HW = 361;  off = 7220; pr = p2; }
            int cell = (int)r - off;
            const float* pb = pr + ((size_t)b * 255 + (size_t)a * 85) * (size_t)HW + cell;
            float tx = pb[0];
            float ty = pb[(size_t)HW];
            float tw = pb[(size_t)2 * HW];
            float th = pb[(size_t)3 * HW];
            float Sf = (float)S;
            float gx = (float)(cell % S);
            float gy = (float)(cell / S);
            float cx = (sigf(tx) + gx) / Sf;
            float cy = (sigf(ty) + gy) / Sf;
            float aw = dp.aw[s * 3 + a], ah = dp.ah[s * 3 + a];
            float bw = expf_cr(tw) * aw;
            float bh = expf_cr(th) * ah;
            float x1 = cx - 0.5f * bw;
            float y1 = cy - 0.5f * bh;
            bb = make_float4(x1, y1, x1 + bw, y1 + bh);
        }
        bxs4[t] = bb;
        pvs[t] = vld ? sc : -1.0f;    // dead-unique key -> sc = 0.0 (never kept/suppresses)
    }
    __syncthreads();

    // --- bitmask NMS: parallel IoU mask build, then wave-0 bitmask greedy ---
    {
        int i = t >> 1, h = t & 1;
        float4 bi = bxs4[i];
        float ai = (bi.z - bi.x) * (bi.w - bi.y);
        unsigned long long m = 0;
        int jb = h << 6;
        for (int k = 0; k < 64; ++k) {
            int j = jb + k;
            float4 bj = bxs4[j];
            float aj = (bj.z - bj.x) * (bj.w - bj.y);
            float xx1 = fmaxf(bi.x, bj.x), yy1 = fmaxf(bi.y, bj.y);
            float xx2 = fminf(bi.z, bj.z), yy2 = fminf(bi.w, bj.w);
            float ww = fmaxf(xx2 - xx1, 0.0f), hh = fmaxf(yy2 - yy1, 0.0f);
            float inter = ww * hh;
            float iou = inter / (ai + aj - inter);
            if (j > i && iou > 0.45f) m |= (1ull << k);
        }
        msk[i][h] = m;
    }
    __syncthreads();
    if (t < 64) {
        unsigned long long A0 = __ballot(pvs[t] > 0.0f);
        unsigned long long A1 = __ballot(pvs[t + 64] > 0.0f);
        for (int i = 0; i < 64; ++i) {
            if ((A0 >> i) & 1) { A0 &= ~msk[i][0]; A1 &= ~msk[i][1]; }
        }
        for (int i = 0; i < 64; ++i) {
            if ((A1 >> i) & 1) { A1 &= ~msk[64 + i][1]; }   // msk[i>=64][0] is all-zero (j>i)
        }
        if (t == 0) { aliveLDS[0] = A0; aliveLDS[1] = A1; }
    }
    __syncthreads();

    // --- write [K,6] = x1,y1,x2,y2,score,class ---
    unsigned long long A0 = aliveLDS[0], A1 = aliveLDS[1];
    float* o = out + (size_t)bid * TOPK * 6;
    for (int i = t; i < TOPK; i += 256) {
        bool alive = (i < 64) ? ((A0 >> i) & 1) : ((A1 >> (i - 64)) & 1);
        float p = pvs[i];
        bool kept = alive && (p > 0.0f);
        float4 bb = bxs4[i];
        o[i * 6 + 0] = kept ? bb.x : 0.0f;
        o[i * 6 + 1] = kept ? bb.y : 0.0f;
        o[i * 6 + 2] = kept ? bb.z : 0.0f;
        o[i * 6 + 3] = kept ? bb.w : 0.0f;
        o[i * 6 + 4] = kept ? p : 0.0f;
        o[i * 6 + 5] = (float)c;
    }
}

extern "C" void kernel_launch(void* const* d_in, const int* in_sizes, int n_in,
                              void* d_out, int out_size, void* d_ws, size_t ws_size,
                              hipStream_t stream) {
    const float* p0 = (const float*)d_in[0];
    const float* p1 = (const float*)d_in[1];
    const float* p2 = (const float*)d_in[2];
    float* out = (float*)d_out;

    char* ws = (char*)d_ws;
    unsigned int* gcnt = (unsigned int*)ws;                    // 5120 B (pad 8192)
    float* so_arr = (float*)(ws + 8192);                       // 1,456,128 B
    float* xthr   = (float*)(ws + 1464320ull);                 // 1,456,128 B
    unsigned int* nlist = (unsigned int*)(ws + 2920448ull);    // 1280*2048*4 = 10,485,760 B

    static const float ANC[3][3][2] = {
        {{12, 16}, {19, 36}, {40, 28}},
        {{36, 75}, {76, 55}, {72, 146}},
        {{142, 110}, {192, 243}, {459, 401}},
    };
    static const int RED[3] = {8, 16, 32};
    static const int SS[3]  = {76, 38, 19};

    DecParams dp;
    for (int s = 0; s < 3; ++s)
        for (int a = 0; a < 3; ++a) {
            float Sf = (float)SS[s];
            dp.aw[s * 3 + a] = (ANC[s][a][0] / (float)RED[s]) / Sf;  // same f32 chain as ref
            dp.ah[s * 3 + a] = (ANC[s][a][1] / (float)RED[s]) / Sf;
        }

    hipMemsetAsync(gcnt, 0, BATCH * NCLS * sizeof(unsigned int), stream);
    decode_kernel<<<BATCH * 93, 256, 0, stream>>>(p0, p1, p2, so_arr, xthr);
    scatter_kernel<<<2160, 256, 0, stream>>>(p0, p1, p2, xthr, nlist, gcnt);
    select_nms_kernel<<<BATCH * NCLS, 256, 0, stream>>>(p0, p1, p2, so_arr,
                                                        nlist, gcnt, dp, out);
}

// Round 9
// 77.252 us; speedup vs baseline: 1.3025x; 1.3025x over previous
//
#include <hip/hip_runtime.h>
#include <math.h>

#define BATCH 16
#define NCLS 80
#define SUMHW 7581            // 76*76 + 38*38 + 19*19
#define NN 22743              // 3 anchors * SUMHW
#define ASTRIDE 7584          // padded per-anchor stride for so/xthr (7581 -> 7584, /4)
#define PADNN (3 * ASTRIDE)   // 22752
#define TOPK 128
#define CAP 1024              // fallback gather cap
#define WCAP 512              // per-wave capture list cap (4 waves -> 2048 total)
#define PRUNECAP 512          // post-prune survivor cap
#define KEYBASE 0x3E800000u   // bits of 0.25f (fallback histogram base)
#define KB2     0x3F180000u   // bits of 0.59375f (prune histogram base)
#define SBITS   0x3F19999Au   // bits of 0.6f

// exact sigmoid matching numpy f32 chain: correctly-rounded exp (double) -> f32 ops
__device__ __forceinline__ float sigf(float x) {
    float e = (float)exp(-(double)x);
    return 1.0f / (1.0f + e);
}
__device__ __forceinline__ float expf_cr(float x) {
    return (float)exp((double)x);
}

struct DecParams { float aw[9]; float ah[9]; };

// ---------------- Stage A: exact objectness + x-threshold (obj channel only, float4) ----
// xthr correctness (r5-r8 validated):
//   Tp = 0.59999 (< 0.6f).  thr = -log(so/Tp - 1)  =>  sigmoid(thr) = Tp/so.
//   ex >= 0.6f  =>  x > thr (captured).   x <= thr  =>  ex < 0.6f (safe to miss).
//   so <= 0.59999f  =>  ex < 0.6f  =>  xthr=+INF.
__global__ __launch_bounds__(256) void decode_kernel(
        const float* __restrict__ p0, const float* __restrict__ p1,
        const float* __restrict__ p2,
        float* __restrict__ so_arr, float* __restrict__ xthr_arr) {
    int blk = blockIdx.x;              // 16 b * 3 a * 9 segs = 432
    int b = blk / 27;
    int rem = blk % 27;
    int a = rem / 9;
    int seg = rem % 9;
    int s, segi;
    if (seg < 6)      { s = 0; segi = seg; }
    else if (seg < 8) { s = 1; segi = seg - 6; }
    else              { s = 2; segi = 0; }
    const int HW_[3]  = {5776, 1444, 361};
    const int OFF_[3] = {0, 5776, 7220};
    const float* __restrict__ pr = (s == 0) ? p0 : (s == 1) ? p1 : p2;
    int HW = HW_[s], OFF = OFF_[s];
    int t = threadIdx.x;

    auto mkthr = [](float so) {
        float thr = __int_as_float(0x7F800000);       // +INF
        if (so > 0.59999f) {
            double arg = (double)so / 0.59999 - 1.0;
            thr = __double2float_rd(-log(arg));       // round DOWN: conservative capture
        }
        return thr;
    };

    if (s != 2) {
        int cell0 = segi * 1024 + t * 4;
        if (cell0 >= HW) return;                      // active threads are full float4s
        const float4* ob4 =
            (const float4*)(pr + ((size_t)b * 255 + (size_t)a * 85 + 4) * (size_t)HW);
        float4 ov = ob4[cell0 >> 2];
        float4 sov, thv;
        sov.x = sigf(ov.x); thv.x = mkthr(sov.x);
        sov.y = sigf(ov.y); thv.y = mkthr(sov.y);
        sov.z = sigf(ov.z); thv.z = mkthr(sov.z);
        sov.w = sigf(ov.w); thv.w = mkthr(sov.w);
        size_t pidx = (size_t)b * PADNN + a * ASTRIDE + OFF + cell0;
        *(float4*)(so_arr + pidx)   = sov;
        *(float4*)(xthr_arr + pidx) = thv;
    } else {
        const float* ob = pr + ((size_t)b * 255 + (size_t)a * 85 + 4) * 361;
        for (int i = t; i < 361; i += 256) {
            float so = sigf(ob[i]);
            size_t pidx = (size_t)b * PADNN + a * ASTRIDE + 7220 + i;
            so_arr[pidx] = so;
            xthr_arr[pidx] = mkthr(so);
        }
    }
}

// ------- Stage B (fused): per-(b,c) compare-scan + prune + exact rescore +
//         rank-select + lazy box decode + bitmask NMS. No global intermediates. -------
__global__ __launch_bounds__(256) void select_nms_kernel(
        const float* __restrict__ p0, const float* __restrict__ p1,
        const float* __restrict__ p2,
        const float* __restrict__ so_arr,
        const float* __restrict__ xthr_arr,
        DecParams dp,
        float* __restrict__ out) {
    // 24KB aliased pool:
    //   [0,8K)    wn (scan lists)  -> later skey (rescore/fallback keys)
    //   [8K,16K)  kbuf (approx keys) -> later sorted/msk
    //   [16K,24K) nbuf (cand idx)    -> later bxs4/pvs
    __shared__ __attribute__((aligned(16))) unsigned char smem[24576];
    unsigned int* wn        = (unsigned int*)smem;
    unsigned long long* skey = (unsigned long long*)smem;
    unsigned int* kbuf      = (unsigned int*)(smem + 8192);
    unsigned int* nbuf      = (unsigned int*)(smem + 16384);
    unsigned long long* sorted = (unsigned long long*)(smem + 8192);    // 1KB
    unsigned long long* mskp   = (unsigned long long*)(smem + 9216);    // 2KB msk[i][h]
    float4* bxs4            = (float4*)(smem + 16384);                  // 2KB
    float*  pvs             = (float*)(smem + 18432);                   // 512B
    __shared__ unsigned int hist[512];
    __shared__ unsigned int sums[256];
    __shared__ unsigned int wvc[4];
    __shared__ unsigned long long aliveLDS[2];
    __shared__ unsigned int sh_bin, sh_above, gcount;

    int t = threadIdx.x;
    int w = t >> 6, lane = t & 63;
    int bid = blockIdx.x;          // b*80 + c
    int b = bid / NCLS;
    int c = bid % NCLS;

    if (t < 4) wvc[t] = 0;
    __syncthreads();

    // --- compare-only scan: x > xthr  => capture n into this wave's LDS list ---
#define PUSH(nn) { unsigned pos = atomicAdd(&wvc[w], 1u); \
                   if (pos < WCAP) wn[w * WCAP + pos] = (unsigned)(nn); }
#pragma unroll
    for (int s = 0; s < 2; ++s) {               // s0/s1: float4 (HW % 4 == 0)
        const float* __restrict__ pr = (s == 0) ? p0 : p1;
        const int HW  = (s == 0) ? 5776 : 1444;
        const int OFF = (s == 0) ? 0 : 5776;
#pragma unroll
        for (int a = 0; a < 3; ++a) {
            const float4* __restrict__ cp4 =
                (const float4*)(pr + ((size_t)b * 255 + (size_t)a * 85 + 5 + (size_t)c) * (size_t)HW);
            const float4* __restrict__ xt4 =
                (const float4*)(xthr_arr + (size_t)b * PADNN + a * ASTRIDE + OFF);
            int n0 = a * SUMHW + OFF;
            int nq = HW >> 2;
            for (int i = t; i < nq; i += 256) {
                float4 xv = cp4[i];
                float4 tv = xt4[i];
                int nb = n0 + 4 * i;
                if (xv.x > tv.x) PUSH(nb);
                if (xv.y > tv.y) PUSH(nb + 1);
                if (xv.z > tv.z) PUSH(nb + 2);
                if (xv.w > tv.w) PUSH(nb + 3);
            }
        }
    }
#pragma unroll
    for (int a = 0; a < 3; ++a) {               // s2: 361 cells, scalar
        const float* __restrict__ cp =
            p2 + ((size_t)b * 255 + (size_t)a * 85 + 5 + (size_t)c) * 361;
        const float* __restrict__ xt = xthr_arr + (size_t)b * PADNN + a * ASTRIDE + 7220;
        int n0 = a * SUMHW + 7220;
        for (int i = t; i < 361; i += 256) {
            if (cp[i] > xt[i]) PUSH(n0 + i);
        }
    }
#undef PUSH
    __syncthreads();

    unsigned cw0 = wvc[0], cw1 = wvc[1], cw2 = wvc[2], cw3 = wvc[3];
    bool ovf = (cw0 > WCAP) || (cw1 > WCAP) || (cw2 > WCAP) || (cw3 > WCAP);
    unsigned G = cw0 + cw1 + cw2 + cw3;          // valid only if !ovf
    // G < TOPK => true top-128 needs sub-0.6 elements the scan never captured
    bool fb = ovf || (G < TOPK);

    // all-pairs rank selection: keys unique (low bits carry ~n) => rank is a permutation
    auto rankSelect = [&](unsigned Gc) {
        if (t < TOPK) sorted[t] = 0ULL;
        __syncthreads();
        unsigned i0 = t, i1 = t + 256, i2 = t + 512, i3 = t + 768;
        bool v0 = i0 < Gc, v1 = i1 < Gc, v2 = i2 < Gc, v3 = i3 < Gc;
        unsigned long long o0 = v0 ? skey[i0] : 0ULL;
        unsigned long long o1 = v1 ? skey[i1] : 0ULL;
        unsigned long long o2 = v2 ? skey[i2] : 0ULL;
        unsigned long long o3 = v3 ? skey[i3] : 0ULL;
        unsigned r0 = 0, r1 = 0, r2 = 0, r3 = 0;
        for (unsigned j = 0; j < Gc; ++j) {
            unsigned long long kj = skey[j];      // wave-uniform addr -> LDS broadcast
            r0 += (kj > o0); r1 += (kj > o1); r2 += (kj > o2); r3 += (kj > o3);
        }
        if (v0 && r0 < TOPK) sorted[r0] = o0;
        if (v1 && r1 < TOPK) sorted[r1] = o1;
        if (v2 && r2 < TOPK) sorted[r2] = o2;
        if (v3 && r3 < TOPK) sorted[r3] = o3;
        __syncthreads();
    };

    if (!fb) {
        // --- key-build + compact: each wave handles its own list ---
        unsigned woff = 0;
        if (w > 0) woff += cw0;
        if (w > 1) woff += cw1;
        if (w > 2) woff += cw2;
        unsigned mycnt = (w == 0) ? cw0 : (w == 1) ? cw1 : (w == 2) ? cw2 : cw3;
        for (unsigned i = lane; i < mycnt; i += 64) {
            unsigned n = wn[w * WCAP + i];
            unsigned a = n / SUMHW;
            unsigned r = n - a * SUMHW;
            size_t cb = (size_t)b * 255 + (size_t)a * 85 + 5 + (size_t)c;
            float x;
            if (r < 5776u)      x = p0[cb * 5776 + r];
            else if (r < 7220u) x = p1[cb * 1444 + (r - 5776u)];
            else                x = p2[cb * 361  + (r - 7220u)];
            float so = so_arr[(size_t)b * PADNN + a * ASTRIDE + r];
            float st = 1.0f / (1.0f + __expf(-x));   // approx sigmoid, err few ulp
            kbuf[woff + i] = __float_as_uint(st * so);   // ~>=0.5999 > KB2 always
            nbuf[woff + i] = n;
        }
        for (int i = t; i < 512; i += 256) hist[i] = 0;
        if (t == 0) gcount = 0;
        __syncthreads();                           // kbuf complete; wn dead from here

        // --- pass 1: 512-bin histogram of approx keys (16384-ulp bins) ---
        for (unsigned i = t; i < G; i += 256) {
            unsigned bin = (kbuf[i] - KB2) >> 14;
            if (bin > 511u) bin = 511u;
            atomicAdd(&hist[bin], 1u);
        }
        __syncthreads();
        unsigned m0 = hist[2 * t], m1 = hist[2 * t + 1];
        sums[t] = m0 + m1;
        __syncthreads();
        for (int d = 1; d < 256; d <<= 1) {
            unsigned v = sums[t];
            if (t + d < 256) v += sums[t + d];
            __syncthreads();
            sums[t] = v;
            __syncthreads();
        }
        unsigned si = sums[t], se = si - (m0 + m1);
        if (se < TOPK && TOPK <= si) {              // unique crossing thread
            if (TOPK <= se + m1) { sh_bin = 2 * t + 1; sh_above = se; }
            else                 { sh_bin = 2 * t;     sh_above = se + m1; }
        }
        __syncthreads();
        unsigned B1 = sh_bin, above1 = sh_above;
        unsigned cntB = hist[B1];
        unsigned binlo = KB2 + (B1 << 14);
        if (above1 + cntB > PRUNECAP - 64) {
            fb = true;                               // fat bin (~never): full re-scan
        } else {
            // --- pass 2: keep keys >= binlo - 256ulp (r3-validated margin);
            //             exact-rescore survivors only (reference-identical chain) ---
            unsigned gth = binlo - 256;
            for (unsigned i = t; i < G; i += 256) {
                if (kbuf[i] >= gth) {
                    unsigned pos = atomicAdd(&gcount, 1u);
                    if (pos < PRUNECAP) {
                        unsigned n = nbuf[i];
                        unsigned a = n / SUMHW;
                        unsigned r = n - a * SUMHW;
                        size_t cb = (size_t)b * 255 + (size_t)a * 85 + 5 + (size_t)c;
                        float x;
                        if (r < 5776u)      x = p0[cb * 5776 + r];
                        else if (r < 7220u) x = p1[cb * 1444 + (r - 5776u)];
                        else                x = p2[cb * 361  + (r - 7220u)];
                        float so = so_arr[(size_t)b * PADNN + a * ASTRIDE + r];
                        float ex = so * sigf(x);
                        skey[pos] = (ex > 0.3f)
                            ? (((unsigned long long)__float_as_uint(ex) << 32) |
                               (unsigned)(~n))
                            : (unsigned long long)(unsigned)(~n);   // unique dead key
                    }
                }
            }
            __syncthreads();
            if (gcount > PRUNECAP) fb = true;        // overflow (~never): full re-scan
            if (!fb) {
                unsigned Gc = gcount;
                rankSelect(Gc);
                // success <=> kept 128th has ex >= 0.6f (every scan-missed elem < 0.6f)
                bool ok = (Gc >= TOPK) && ((unsigned)(sorted[TOPK - 1] >> 32) >= SBITS);
                if (!ok) fb = true;
            }
        }
    }

    if (fb) {
        // ---- full re-scan fallback (rounds 3/4 validated); never taken on bench data ----
        auto scanScalar = [&](auto&& body) {
#pragma unroll
            for (int s = 0; s < 3; ++s) {
                const float* __restrict__ pr = (s == 0) ? p0 : (s == 1) ? p1 : p2;
                const int HW  = (s == 0) ? 5776 : (s == 1) ? 1444 : 361;
                const int OFF = (s == 0) ? 0 : (s == 1) ? 5776 : 7220;
#pragma unroll
                for (int a = 0; a < 3; ++a) {
                    const float* __restrict__ cp =
                        pr + ((size_t)b * 255 + (size_t)a * 85 + 5 + (size_t)c) * (size_t)HW;
                    const float* __restrict__ sop =
                        so_arr + (size_t)b * PADNN + a * ASTRIDE + OFF;
                    int n0 = a * SUMHW + OFF;
                    for (int i = t; i < HW; i += 256) {
                        float so = sop[i];
                        if (so <= 0.2999f) continue;
                        float x = cp[i];
                        float st = 1.0f / (1.0f + __expf(-x));
                        float sca = st * so;
                        if (sca > 0.2999f) body(sca, x, so, n0 + i);
                    }
                }
            }
        };
        __syncthreads();
        for (int i = t; i < 512; i += 256) hist[i] = 0;
        if (t == 0) gcount = 0;
        __syncthreads();
        scanScalar([&](float sca, float, float, int) {
            unsigned bin = (__float_as_uint(sca) - KEYBASE) >> 15;
            if (bin > 511u) bin = 511u;
            atomicAdd(&hist[bin], 1u);
        });
        __syncthreads();
        unsigned m0 = hist[2 * t], m1 = hist[2 * t + 1];
        sums[t] = m0 + m1;
        __syncthreads();
        for (int d = 1; d < 256; d <<= 1) {
            unsigned v = sums[t];
            if (t + d < 256) v += sums[t + d];
            __syncthreads();
            sums[t] = v;
            __syncthreads();
        }
        unsigned total = sums[0];
        bool gatherAll = (total < TOPK);
        unsigned gth = 0;
        if (!gatherAll) {
            unsigned si = sums[t], se = si - (m0 + m1);
            if (se < TOPK && TOPK <= si) {
                if (TOPK <= se + m1) { sh_bin = 2 * t + 1; sh_above = se; }
                else                 { sh_bin = 2 * t;     sh_above = se + m1; }
            }
            __syncthreads();
            unsigned B1 = sh_bin, above1 = sh_above;
            unsigned cntB = hist[B1];
            unsigned binlo = KEYBASE + (B1 << 15);
            __syncthreads();
            if (above1 + cntB <= 768) {
                gth = binlo - 256;
            } else {
                if (t < 256) hist[t] = 0;
                __syncthreads();
                scanScalar([&](float sca, float, float, int) {
                    unsigned key = __float_as_uint(sca);
                    if (((key - KEYBASE) >> 15) == B1) {
                        unsigned sub = (key - binlo) >> 7;
                        if (sub > 255u) sub = 255u;
                        atomicAdd(&hist[sub], 1u);
                    }
                });
                __syncthreads();
                unsigned R2 = TOPK - above1;
                unsigned sl = hist[t];
                sums[t] = sl;
                __syncthreads();
                for (int d = 1; d < 256; d <<= 1) {
                    unsigned v = sums[t];
                    if (t + d < 256) v += sums[t + d];
                    __syncthreads();
                    sums[t] = v;
                    __syncthreads();
                }
                unsigned si2 = sums[t], se2 = si2 - sl;
                if (se2 < R2 && R2 <= si2) sh_bin = (unsigned)t;
                __syncthreads();
                gth = binlo + (sh_bin << 7) - 256;
            }
        }
        __syncthreads();
        scanScalar([&](float sca, float x, float so, int n) {
            unsigned key = __float_as_uint(sca);
            if (gatherAll || key >= gth) {
                unsigned pos = atomicAdd(&gcount, 1u);
                if (pos < CAP) {
                    float ex = so * sigf(x);
                    skey[pos] = (ex > 0.3f)
                        ? (((unsigned long long)__float_as_uint(ex) << 32) |
                           (unsigned)(~(unsigned)n))
                        : (unsigned long long)(unsigned)(~(unsigned)n);
                }
            }
        });
        __syncthreads();
        unsigned Gc = gcount < CAP ? gcount : CAP;
        rankSelect(Gc);
    }

    // --- extract top-128 + LAZY box decode (reference-identical f32 chain) ---
    if (t < TOPK) {
        unsigned long long e = sorted[t];
        bool vld = (e != 0ULL);
        float sc = __uint_as_float((unsigned)(e >> 32));
        unsigned n = ~(unsigned)(e & 0xFFFFFFFFu);
        float4 bb = make_float4(0.f, 0.f, 0.f, 0.f);
        if (vld) {
            unsigned a = n / SUMHW;
            unsigned r = n - a * SUMHW;
            int s, S, HW, off; const float* pr;
            if (r < 5776u)      { s = 0; S = 76; HW = 5776; off = 0;    pr = p0; }
            else if (r < 7220u) { s = 1; S = 38; HW = 1444; off = 5776; pr = p1; }
            else                { s = 2; S = 19; HW = 361;  off = 7220; pr = p2; }
            int cell = (int)r - off;
            const float* pb = pr + ((size_t)b * 255 + (size_t)a * 85) * (size_t)HW + cell;
            float tx = pb[0];
            float ty = pb[(size_t)HW];
            float tw = pb[(size_t)2 * HW];
            float th = pb[(size_t)3 * HW];
            float Sf = (float)S;
            float gx = (float)(cell % S);
            float gy = (float)(cell / S);
            float cx = (sigf(tx) + gx) / Sf;
            float cy = (sigf(ty) + gy) / Sf;
            float aw = dp.aw[s * 3 + a], ah = dp.ah[s * 3 + a];
            float bw = expf_cr(tw) * aw;
            float bh = expf_cr(th) * ah;
            float x1 = cx - 0.5f * bw;
            float y1 = cy - 0.5f * bh;
            bb = make_float4(x1, y1, x1 + bw, y1 + bh);
        }
        bxs4[t] = bb;
        pvs[t] = vld ? sc : -1.0f;    // dead-unique key -> sc = 0.0 (never kept/suppresses)
    }
    __syncthreads();

    // --- bitmask NMS: parallel IoU mask build, then wave-0 bitmask greedy ---
    {
        int i = t >> 1, h = t & 1;
        float4 bi = bxs4[i];
        float ai = (bi.z - bi.x) * (bi.w - bi.y);
        unsigned long long m = 0;
        int jb = h << 6;
        for (int k = 0; k < 64; ++k) {
            int j = jb + k;
            float4 bj = bxs4[j];
            float aj = (bj.z - bj.x) * (bj.w - bj.y);
            float xx1 = fmaxf(bi.x, bj.x), yy1 = fmaxf(bi.y, bj.y);
            float xx2 = fminf(bi.z, bj.z), yy2 = fminf(bi.w, bj.w);
            float ww = fmaxf(xx2 - xx1, 0.0f), hh = fmaxf(yy2 - yy1, 0.0f);
            float inter = ww * hh;
            float iou = inter / (ai + aj - inter);
            if (j > i && iou > 0.45f) m |= (1ull << k);
        }
        mskp[(i << 1) | h] = m;
    }
    __syncthreads();
    if (t < 64) {
        unsigned long long A0 = __ballot(pvs[t] > 0.0f);
        unsigned long long A1 = __ballot(pvs[t + 64] > 0.0f);
        for (int i = 0; i < 64; ++i) {
            if ((A0 >> i) & 1) { A0 &= ~mskp[i << 1]; A1 &= ~mskp[(i << 1) | 1]; }
        }
        for (int i = 0; i < 64; ++i) {
            if ((A1 >> i) & 1) { A1 &= ~mskp[((64 + i) << 1) | 1]; }  // lower half: j>i => 0
        }
        if (t == 0) { aliveLDS[0] = A0; aliveLDS[1] = A1; }
    }
    __syncthreads();

    // --- write [K,6] = x1,y1,x2,y2,score,class ---
    unsigned long long A0 = aliveLDS[0], A1 = aliveLDS[1];
    float* o = out + (size_t)bid * TOPK * 6;
    for (int i = t; i < TOPK; i += 256) {
        bool alive = (i < 64) ? ((A0 >> i) & 1) : ((A1 >> (i - 64)) & 1);
        float p = pvs[i];
        bool kept = alive && (p > 0.0f);
        float4 bb = bxs4[i];
        o[i * 6 + 0] = kept ? bb.x : 0.0f;
        o[i * 6 + 1] = kept ? bb.y : 0.0f;
        o[i * 6 + 2] = kept ? bb.z : 0.0f;
        o[i * 6 + 3] = kept ? bb.w : 0.0f;
        o[i * 6 + 4] = kept ? p : 0.0f;
        o[i * 6 + 5] = (float)c;
    }
}

extern "C" void kernel_launch(void* const* d_in, const int* in_sizes, int n_in,
                              void* d_out, int out_size, void* d_ws, size_t ws_size,
                              hipStream_t stream) {
    const float* p0 = (const float*)d_in[0];
    const float* p1 = (const float*)d_in[1];
    const float* p2 = (const float*)d_in[2];
    float* out = (float*)d_out;

    char* ws = (char*)d_ws;
    float* so_arr = (float*)ws;                    // 1,456,128 B
    float* xthr   = (float*)(ws + 1456128ull);     // 1,456,128 B

    static const float ANC[3][3][2] = {
        {{12, 16}, {19, 36}, {40, 28}},
        {{36, 75}, {76, 55}, {72, 146}},
        {{142, 110}, {192, 243}, {459, 401}},
    };
    static const int RED[3] = {8, 16, 32};
    static const int SS[3]  = {76, 38, 19};

    DecParams dp;
    for (int s = 0; s < 3; ++s)
        for (int a = 0; a < 3; ++a) {
            float Sf = (float)SS[s];
            dp.aw[s * 3 + a] = (ANC[s][a][0] / (float)RED[s]) / Sf;  // same f32 chain as ref
            dp.ah[s * 3 + a] = (ANC[s][a][1] / (float)RED[s]) / Sf;
        }

    decode_kernel<<<BATCH * 27, 256, 0, stream>>>(p0, p1, p2, so_arr, xthr);
    select_nms_kernel<<<BATCH * NCLS, 256, 0, stream>>>(p0, p1, p2, so_arr, xthr, dp, out);
}

// Round 10
// 74.003 us; speedup vs baseline: 1.3597x; 1.0439x over previous
//
#include <hip/hip_runtime.h>
#include <math.h>
#include <stdint.h>

#define BATCH 16
#define NCLS 80
#define SUMHW 7581            // 76*76 + 38*38 + 19*19
#define NN 22743              // 3 anchors * SUMHW
#define ASTRIDE 7584          // padded per-anchor stride for so/xthr (7581 -> 7584, /4)
#define PADNN (3 * ASTRIDE)   // 22752
#define TOPK 128
#define CAP 1024              // fallback gather cap
#define WCAP 512              // per-wave capture list cap (4 waves -> 2048 total)
#define PRUNECAP 512          // post-prune survivor cap
#define KEYBASE 0x3E800000u   // bits of 0.25f (fallback histogram base)
#define KB2     0x3F180000u   // bits of 0.59375f (prune histogram base)
#define SBITS   0x3F19999Au   // bits of 0.6f

typedef float f32x4 __attribute__((ext_vector_type(4)));

// exact sigmoid matching numpy f32 chain: correctly-rounded exp (double) -> f32 ops
__device__ __forceinline__ float sigf(float x) {
    float e = (float)exp(-(double)x);
    return 1.0f / (1.0f + e);
}
__device__ __forceinline__ float expf_cr(float x) {
    return (float)exp((double)x);
}

struct DecParams { float aw[9]; float ah[9]; };

// ---------------- Stage A: exact objectness + x-threshold (obj channel only, float4) ----
// xthr correctness (r5-r9 validated):
//   Tp = 0.59999 (< 0.6f).  thr = -log(so/Tp - 1)  =>  sigmoid(thr) = Tp/so.
//   ex >= 0.6f  =>  x > thr (captured).   x <= thr  =>  ex < 0.6f (safe to miss).
//   so <= 0.59999f  =>  ex < 0.6f  =>  xthr=+INF.
__global__ __launch_bounds__(256) void decode_kernel(
        const float* __restrict__ p0, const float* __restrict__ p1,
        const float* __restrict__ p2,
        float* __restrict__ so_arr, float* __restrict__ xthr_arr) {
    int blk = blockIdx.x;              // 16 b * 3 a * 9 segs = 432
    int b = blk / 27;
    int rem = blk % 27;
    int a = rem / 9;
    int seg = rem % 9;
    int s, segi;
    if (seg < 6)      { s = 0; segi = seg; }
    else if (seg < 8) { s = 1; segi = seg - 6; }
    else              { s = 2; segi = 0; }
    const int HW_[3]  = {5776, 1444, 361};
    const int OFF_[3] = {0, 5776, 7220};
    const float* __restrict__ pr = (s == 0) ? p0 : (s == 1) ? p1 : p2;
    int HW = HW_[s], OFF = OFF_[s];
    int t = threadIdx.x;

    auto mkthr = [](float so) {
        float thr = __int_as_float(0x7F800000);       // +INF
        if (so > 0.59999f) {
            double arg = (double)so / 0.59999 - 1.0;
            thr = __double2float_rd(-log(arg));       // round DOWN: conservative capture
        }
        return thr;
    };

    if (s != 2) {
        int cell0 = segi * 1024 + t * 4;
        if (cell0 >= HW) return;                      // active threads are full float4s
        const float4* ob4 =
            (const float4*)(pr + ((size_t)b * 255 + (size_t)a * 85 + 4) * (size_t)HW);
        float4 ov = ob4[cell0 >> 2];
        float4 sov, thv;
        sov.x = sigf(ov.x); thv.x = mkthr(sov.x);
        sov.y = sigf(ov.y); thv.y = mkthr(sov.y);
        sov.z = sigf(ov.z); thv.z = mkthr(sov.z);
        sov.w = sigf(ov.w); thv.w = mkthr(sov.w);
        size_t pidx = (size_t)b * PADNN + a * ASTRIDE + OFF + cell0;
        *(float4*)(so_arr + pidx)   = sov;
        *(float4*)(xthr_arr + pidx) = thv;
    } else {
        const float* ob = pr + ((size_t)b * 255 + (size_t)a * 85 + 4) * 361;
        for (int i = t; i < 361; i += 256) {
            float so = sigf(ob[i]);
            size_t pidx = (size_t)b * PADNN + a * ASTRIDE + 7220 + i;
            so_arr[pidx] = so;
            xthr_arr[pidx] = mkthr(so);
        }
    }
}

// ------- Stage B (fused): per-(b,c) asm-batched compare-scan + prune + exact rescore +
//         rank-select + lazy box decode + bitmask NMS. No global intermediates. -------
__global__ __launch_bounds__(256) void select_nms_kernel(
        const float* __restrict__ p0, const float* __restrict__ p1,
        const float* __restrict__ p2,
        const float* __restrict__ so_arr,
        const float* __restrict__ xthr_arr,
        DecParams dp,
        float* __restrict__ out) {
    // 24KB aliased pool:
    //   [0,8K)    wn (scan lists)  -> later skey (rescore/fallback keys)
    //   [8K,16K)  kbuf (approx keys) -> later sorted/msk
    //   [16K,24K) nbuf (cand idx)    -> later bxs4/pvs
    __shared__ __attribute__((aligned(16))) unsigned char smem[24576];
    unsigned int* wn        = (unsigned int*)smem;
    unsigned long long* skey = (unsigned long long*)smem;
    unsigned int* kbuf      = (unsigned int*)(smem + 8192);
    unsigned int* nbuf      = (unsigned int*)(smem + 16384);
    unsigned long long* sorted = (unsigned long long*)(smem + 8192);    // 1KB
    unsigned long long* mskp   = (unsigned long long*)(smem + 9216);    // 2KB msk[i][h]
    float4* bxs4            = (float4*)(smem + 16384);                  // 2KB
    float*  pvs             = (float*)(smem + 18432);                   // 512B
    __shared__ unsigned int hist[512];
    __shared__ unsigned int sums[256];
    __shared__ unsigned int wvc[4];
    __shared__ unsigned long long aliveLDS[2];
    __shared__ unsigned int sh_bin, sh_above, gcount;

    int t = threadIdx.x;
    int w = t >> 6, lane = t & 63;
    int bid = blockIdx.x;          // b*80 + c
    int b = bid / NCLS;
    int c = bid % NCLS;

    if (t < 4) wvc[t] = 0;
    __syncthreads();

    // --- compare-only scan, anchor-fused, asm-batched (6 loads in flight) ---
#pragma unroll
    for (int s = 0; s < 2; ++s) {               // s0/s1: float4 (HW % 4 == 0)
        const float* __restrict__ pr = (s == 0) ? p0 : p1;
        const int HW  = (s == 0) ? 5776 : 1444;
        const int OFF = (s == 0) ? 0 : 5776;
        const int nq  = HW >> 2;
        unsigned long long bx0 = (unsigned long long)(uintptr_t)
            (pr + ((size_t)b * 255 + 0 * 85 + 5 + (size_t)c) * (size_t)HW);
        unsigned long long bx1 = (unsigned long long)(uintptr_t)
            (pr + ((size_t)b * 255 + 1 * 85 + 5 + (size_t)c) * (size_t)HW);
        unsigned long long bx2 = (unsigned long long)(uintptr_t)
            (pr + ((size_t)b * 255 + 2 * 85 + 5 + (size_t)c) * (size_t)HW);
        unsigned long long bq0 = (unsigned long long)(uintptr_t)
            (xthr_arr + (size_t)b * PADNN + 0 * ASTRIDE + OFF);
        unsigned long long bq1 = (unsigned long long)(uintptr_t)
            (xthr_arr + (size_t)b * PADNN + 1 * ASTRIDE + OFF);
        unsigned long long bq2 = (unsigned long long)(uintptr_t)
            (xthr_arr + (size_t)b * PADNN + 2 * ASTRIDE + OFF);
        for (int i = t; i < nq; i += 256) {
            unsigned voff = (unsigned)i << 4;    // byte offset, shared by all 6 strips
            f32x4 x0, x1, x2, q0, q1, q2;
            asm volatile(
                "global_load_dwordx4 %0, %6, %7\n\t"
                "global_load_dwordx4 %1, %6, %8\n\t"
                "global_load_dwordx4 %2, %6, %9\n\t"
                "global_load_dwordx4 %3, %6, %10\n\t"
                "global_load_dwordx4 %4, %6, %11\n\t"
                "global_load_dwordx4 %5, %6, %12\n\t"
                "s_waitcnt vmcnt(0)"
                : "=&v"(x0), "=&v"(x1), "=&v"(x2),
                  "=&v"(q0), "=&v"(q1), "=&v"(q2)
                : "v"(voff), "s"(bx0), "s"(bx1), "s"(bx2),
                  "s"(bq0), "s"(bq1), "s"(bq2));
            unsigned m = 0;
            m |= (x0.x > q0.x) ? 0x001u : 0u;  m |= (x0.y > q0.y) ? 0x002u : 0u;
            m |= (x0.z > q0.z) ? 0x004u : 0u;  m |= (x0.w > q0.w) ? 0x008u : 0u;
            m |= (x1.x > q1.x) ? 0x010u : 0u;  m |= (x1.y > q1.y) ? 0x020u : 0u;
            m |= (x1.z > q1.z) ? 0x040u : 0u;  m |= (x1.w > q1.w) ? 0x080u : 0u;
            m |= (x2.x > q2.x) ? 0x100u : 0u;  m |= (x2.y > q2.y) ? 0x200u : 0u;
            m |= (x2.z > q2.z) ? 0x400u : 0u;  m |= (x2.w > q2.w) ? 0x800u : 0u;
            if (m) {
                int cellb = OFF + 4 * i;
                do {
                    int k = __ffs(m) - 1;
                    m &= m - 1;
                    int a = k >> 2, j = k & 3;
                    unsigned pos = atomicAdd(&wvc[w], 1u);
                    if (pos < WCAP) wn[w * WCAP + pos] =
                        (unsigned)(a * SUMHW + cellb + j);
                } while (m);
            }
        }
    }
#pragma unroll
    for (int a = 0; a < 3; ++a) {               // s2: 361 cells, scalar
        const float* __restrict__ cp =
            p2 + ((size_t)b * 255 + (size_t)a * 85 + 5 + (size_t)c) * 361;
        const float* __restrict__ xt = xthr_arr + (size_t)b * PADNN + a * ASTRIDE + 7220;
        int n0 = a * SUMHW + 7220;
        for (int i = t; i < 361; i += 256) {
            if (cp[i] > xt[i]) {
                unsigned pos = atomicAdd(&wvc[w], 1u);
                if (pos < WCAP) wn[w * WCAP + pos] = (unsigned)(n0 + i);
            }
        }
    }
    __syncthreads();

    unsigned cw0 = wvc[0], cw1 = wvc[1], cw2 = wvc[2], cw3 = wvc[3];
    bool ovf = (cw0 > WCAP) || (cw1 > WCAP) || (cw2 > WCAP) || (cw3 > WCAP);
    unsigned G = cw0 + cw1 + cw2 + cw3;          // valid only if !ovf
    // G < TOPK => true top-128 needs sub-0.6 elements the scan never captured
    bool fb = ovf || (G < TOPK);

    // all-pairs rank selection: keys unique (low bits carry ~n) => rank is a permutation
    auto rankSelect = [&](unsigned Gc) {
        if (t < TOPK) sorted[t] = 0ULL;
        __syncthreads();
        unsigned i0 = t, i1 = t + 256, i2 = t + 512, i3 = t + 768;
        bool v0 = i0 < Gc, v1 = i1 < Gc, v2 = i2 < Gc, v3 = i3 < Gc;
        unsigned long long o0 = v0 ? skey[i0] : 0ULL;
        unsigned long long o1 = v1 ? skey[i1] : 0ULL;
        unsigned long long o2 = v2 ? skey[i2] : 0ULL;
        unsigned long long o3 = v3 ? skey[i3] : 0ULL;
        unsigned r0 = 0, r1 = 0, r2 = 0, r3 = 0;
        for (unsigned j = 0; j < Gc; ++j) {
            unsigned long long kj = skey[j];      // wave-uniform addr -> LDS broadcast
            r0 += (kj > o0); r1 += (kj > o1); r2 += (kj > o2); r3 += (kj > o3);
        }
        if (v0 && r0 < TOPK) sorted[r0] = o0;
        if (v1 && r1 < TOPK) sorted[r1] = o1;
        if (v2 && r2 < TOPK) sorted[r2] = o2;
        if (v3 && r3 < TOPK) sorted[r3] = o3;
        __syncthreads();
    };

    if (!fb) {
        // --- key-build + compact: each wave handles its own list ---
        unsigned woff = 0;
        if (w > 0) woff += cw0;
        if (w > 1) woff += cw1;
        if (w > 2) woff += cw2;
        unsigned mycnt = (w == 0) ? cw0 : (w == 1) ? cw1 : (w == 2) ? cw2 : cw3;
        for (unsigned i = lane; i < mycnt; i += 64) {
            unsigned n = wn[w * WCAP + i];
            unsigned a = n / SUMHW;
            unsigned r = n - a * SUMHW;
            size_t cb = (size_t)b * 255 + (size_t)a * 85 + 5 + (size_t)c;
            float x;
            if (r < 5776u)      x = p0[cb * 5776 + r];
            else if (r < 7220u) x = p1[cb * 1444 + (r - 5776u)];
            else                x = p2[cb * 361  + (r - 7220u)];
            float so = so_arr[(size_t)b * PADNN + a * ASTRIDE + r];
            float st = 1.0f / (1.0f + __expf(-x));   // approx sigmoid, err few ulp
            kbuf[woff + i] = __float_as_uint(st * so);   // ~>=0.5999 > KB2 always
            nbuf[woff + i] = n;
        }
        for (int i = t; i < 512; i += 256) hist[i] = 0;
        if (t == 0) gcount = 0;
        __syncthreads();                           // kbuf complete; wn dead from here

        // --- pass 1: 512-bin histogram of approx keys (16384-ulp bins) ---
        for (unsigned i = t; i < G; i += 256) {
            unsigned bin = (kbuf[i] - KB2) >> 14;
            if (bin > 511u) bin = 511u;
            atomicAdd(&hist[bin], 1u);
        }
        __syncthreads();
        unsigned m0 = hist[2 * t], m1 = hist[2 * t + 1];
        sums[t] = m0 + m1;
        __syncthreads();
        for (int d = 1; d < 256; d <<= 1) {
            unsigned v = sums[t];
            if (t + d < 256) v += sums[t + d];
            __syncthreads();
            sums[t] = v;
            __syncthreads();
        }
        unsigned si = sums[t], se = si - (m0 + m1);
        if (se < TOPK && TOPK <= si) {              // unique crossing thread
            if (TOPK <= se + m1) { sh_bin = 2 * t + 1; sh_above = se; }
            else                 { sh_bin = 2 * t;     sh_above = se + m1; }
        }
        __syncthreads();
        unsigned B1 = sh_bin, above1 = sh_above;
        unsigned cntB = hist[B1];
        unsigned binlo = KB2 + (B1 << 14);
        if (above1 + cntB > PRUNECAP - 64) {
            fb = true;                               // fat bin (~never): full re-scan
        } else {
            // --- pass 2: keep keys >= binlo - 256ulp (r3-validated margin);
            //             exact-rescore survivors only (reference-identical chain) ---
            unsigned gth = binlo - 256;
            for (unsigned i = t; i < G; i += 256) {
                if (kbuf[i] >= gth) {
                    unsigned pos = atomicAdd(&gcount, 1u);
                    if (pos < PRUNECAP) {
                        unsigned n = nbuf[i];
                        unsigned a = n / SUMHW;
                        unsigned r = n - a * SUMHW;
                        size_t cb = (size_t)b * 255 + (size_t)a * 85 + 5 + (size_t)c;
                        float x;
                        if (r < 5776u)      x = p0[cb * 5776 + r];
                        else if (r < 7220u) x = p1[cb * 1444 + (r - 5776u)];
                        else                x = p2[cb * 361  + (r - 7220u)];
                        float so = so_arr[(size_t)b * PADNN + a * ASTRIDE + r];
                        float ex = so * sigf(x);
                        skey[pos] = (ex > 0.3f)
                            ? (((unsigned long long)__float_as_uint(ex) << 32) |
                               (unsigned)(~n))
                            : (unsigned long long)(unsigned)(~n);   // unique dead key
                    }
                }
            }
            __syncthreads();
            if (gcount > PRUNECAP) fb = true;        // overflow (~never): full re-scan
            if (!fb) {
                unsigned Gc = gcount;
                rankSelect(Gc);
                // success <=> kept 128th has ex >= 0.6f (every scan-missed elem < 0.6f)
                bool ok = (Gc >= TOPK) && ((unsigned)(sorted[TOPK - 1] >> 32) >= SBITS);
                if (!ok) fb = true;
            }
        }
    }

    if (fb) {
        // ---- full re-scan fallback (rounds 3/4 validated); never taken on bench data ----
        auto scanScalar = [&](auto&& body) {
#pragma unroll
            for (int s = 0; s < 3; ++s) {
                const float* __restrict__ pr = (s == 0) ? p0 : (s == 1) ? p1 : p2;
                const int HW  = (s == 0) ? 5776 : (s == 1) ? 1444 : 361;
                const int OFF = (s == 0) ? 0 : (s == 1) ? 5776 : 7220;
#pragma unroll
                for (int a = 0; a < 3; ++a) {
                    const float* __restrict__ cp =
                        pr + ((size_t)b * 255 + (size_t)a * 85 + 5 + (size_t)c) * (size_t)HW;
                    const float* __restrict__ sop =
                        so_arr + (size_t)b * PADNN + a * ASTRIDE + OFF;
                    int n0 = a * SUMHW + OFF;
                    for (int i = t; i < HW; i += 256) {
                        float so = sop[i];
                        if (so <= 0.2999f) continue;
                        float x = cp[i];
                        float st = 1.0f / (1.0f + __expf(-x));
                        float sca = st * so;
                        if (sca > 0.2999f) body(sca, x, so, n0 + i);
                    }
                }
            }
        };
        __syncthreads();
        for (int i = t; i < 512; i += 256) hist[i] = 0;
        if (t == 0) gcount = 0;
        __syncthreads();
        scanScalar([&](float sca, float, float, int) {
            unsigned bin = (__float_as_uint(sca) - KEYBASE) >> 15;
            if (bin > 511u) bin = 511u;
            atomicAdd(&hist[bin], 1u);
        });
        __syncthreads();
        unsigned m0 = hist[2 * t], m1 = hist[2 * t + 1];
        sums[t] = m0 + m1;
        __syncthreads();
        for (int d = 1; d < 256; d <<= 1) {
            unsigned v = sums[t];
            if (t + d < 256) v += sums[t + d];
            __syncthreads();
            sums[t] = v;
            __syncthreads();
        }
        unsigned total = sums[0];
        bool gatherAll = (total < TOPK);
        unsigned gth = 0;
        if (!gatherAll) {
            unsigned si = sums[t], se = si - (m0 + m1);
            if (se < TOPK && TOPK <= si) {
                if (TOPK <= se + m1) { sh_bin = 2 * t + 1; sh_above = se; }
                else                 { sh_bin = 2 * t;     sh_above = se + m1; }
            }
            __syncthreads();
            unsigned B1 = sh_bin, above1 = sh_above;
            unsigned cntB = hist[B1];
            unsigned binlo = KEYBASE + (B1 << 15);
            __syncthreads();
            if (above1 + cntB <= 768) {
                gth = binlo - 256;
            } else {
                if (t < 256) hist[t] = 0;
                __syncthreads();
                scanScalar([&](float sca, float, float, int) {
                    unsigned key = __float_as_uint(sca);
                    if (((key - KEYBASE) >> 15) == B1) {
                        unsigned sub = (key - binlo) >> 7;
                        if (sub > 255u) sub = 255u;
                        atomicAdd(&hist[sub], 1u);
                    }
                });
                __syncthreads();
                unsigned R2 = TOPK - above1;
                unsigned sl = hist[t];
                sums[t] = sl;
                __syncthreads();
                for (int d = 1; d < 256; d <<= 1) {
                    unsigned v = sums[t];
                    if (t + d < 256) v += sums[t + d];
                    __syncthreads();
                    sums[t] = v;
                    __syncthreads();
                }
                unsigned si2 = sums[t], se2 = si2 - sl;
                if (se2 < R2 && R2 <= si2) sh_bin = (unsigned)t;
                __syncthreads();
                gth = binlo + (sh_bin << 7) - 256;
            }
        }
        __syncthreads();
        scanScalar([&](float sca, float x, float so, int n) {
            unsigned key = __float_as_uint(sca);
            if (gatherAll || key >= gth) {
                unsigned pos = atomicAdd(&gcount, 1u);
                if (pos < CAP) {
                    float ex = so * sigf(x);
                    skey[pos] = (ex > 0.3f)
                        ? (((unsigned long long)__float_as_uint(ex) << 32) |
                           (unsigned)(~(unsigned)n))
                        : (unsigned long long)(unsigned)(~(unsigned)n);
                }
            }
        });
        __syncthreads();
        unsigned Gc = gcount < CAP ? gcount : CAP;
        rankSelect(Gc);
    }

    // --- extract top-128 + LAZY box decode (reference-identical f32 chain) ---
    if (t < TOPK) {
        unsigned long long e = sorted[t];
        bool vld = (e != 0ULL);
        float sc = __uint_as_float((unsigned)(e >> 32));
        unsigned n = ~(unsigned)(e & 0xFFFFFFFFu);
        float4 bb = make_float4(0.f, 0.f, 0.f, 0.f);
        if (vld) {
            unsigned a = n / SUMHW;
            unsigned r = n - a * SUMHW;
            int s, S, HW, off; const float* pr;
            if (r < 5776u)      { s = 0; S = 76; HW = 5776; off = 0;    pr = p0; }
            else if (r < 7220u) { s = 1; S = 38; HW = 1444; off = 5776; pr = p1; }
            else                { s = 2; S = 19; HW = 361;  off = 7220; pr = p2; }
            int cell = (int)r - off;
            const float* pb = pr + ((size_t)b * 255 + (size_t)a * 85) * (size_t)HW + cell;
            float tx = pb[0];
            float ty = pb[(size_t)HW];
            float tw = pb[(size_t)2 * HW];
            float th = pb[(size_t)3 * HW];
            float Sf = (float)S;
            float gx = (float)(cell % S);
            float gy = (float)(cell / S);
            float cx = (sigf(tx) + gx) / Sf;
            float cy = (sigf(ty) + gy) / Sf;
            float aw = dp.aw[s * 3 + a], ah = dp.ah[s * 3 + a];
            float bw = expf_cr(tw) * aw;
            float bh = expf_cr(th) * ah;
            float x1 = cx - 0.5f * bw;
            float y1 = cy - 0.5f * bh;
            bb = make_float4(x1, y1, x1 + bw, y1 + bh);
        }
        bxs4[t] = bb;
        pvs[t] = vld ? sc : -1.0f;    // dead-unique key -> sc = 0.0 (never kept/suppresses)
    }
    __syncthreads();

    // --- bitmask NMS: parallel IoU mask build, then wave-0 bitmask greedy ---
    {
        int i = t >> 1, h = t & 1;
        float4 bi = bxs4[i];
        float ai = (bi.z - bi.x) * (bi.w - bi.y);
        unsigned long long m = 0;
        int jb = h << 6;
        for (int k = 0; k < 64; ++k) {
            int j = jb + k;
            float4 bj = bxs4[j];
            float aj = (bj.z - bj.x) * (bj.w - bj.y);
            float xx1 = fmaxf(bi.x, bj.x), yy1 = fmaxf(bi.y, bj.y);
            float xx2 = fminf(bi.z, bj.z), yy2 = fminf(bi.w, bj.w);
            float ww = fmaxf(xx2 - xx1, 0.0f), hh = fmaxf(yy2 - yy1, 0.0f);
            float inter = ww * hh;
            float iou = inter / (ai + aj - inter);
            if (j > i && iou > 0.45f) m |= (1ull << k);
        }
        mskp[(i << 1) | h] = m;
    }
    __syncthreads();
    if (t < 64) {
        unsigned long long A0 = __ballot(pvs[t] > 0.0f);
        unsigned long long A1 = __ballot(pvs[t + 64] > 0.0f);
        for (int i = 0; i < 64; ++i) {
            if ((A0 >> i) & 1) { A0 &= ~mskp[i << 1]; A1 &= ~mskp[(i << 1) | 1]; }
        }
        for (int i = 0; i < 64; ++i) {
            if ((A1 >> i) & 1) { A1 &= ~mskp[((64 + i) << 1) | 1]; }  // lower half: j>i => 0
        }
        if (t == 0) { aliveLDS[0] = A0; aliveLDS[1] = A1; }
    }
    __syncthreads();

    // --- write [K,6] = x1,y1,x2,y2,score,class ---
    unsigned long long A0 = aliveLDS[0], A1 = aliveLDS[1];
    float* o = out + (size_t)bid * TOPK * 6;
    for (int i = t; i < TOPK; i += 256) {
        bool alive = (i < 64) ? ((A0 >> i) & 1) : ((A1 >> (i - 64)) & 1);
        float p = pvs[i];
        bool kept = alive && (p > 0.0f);
        float4 bb = bxs4[i];
        o[i * 6 + 0] = kept ? bb.x : 0.0f;
        o[i * 6 + 1] = kept ? bb.y : 0.0f;
        o[i * 6 + 2] = kept ? bb.z : 0.0f;
        o[i * 6 + 3] = kept ? bb.w : 0.0f;
        o[i * 6 + 4] = kept ? p : 0.0f;
        o[i * 6 + 5] = (float)c;
    }
}

extern "C" void kernel_launch(void* const* d_in, const int* in_sizes, int n_in,
                              void* d_out, int out_size, void* d_ws, size_t ws_size,
                              hipStream_t stream) {
    const float* p0 = (const float*)d_in[0];
    const float* p1 = (const float*)d_in[1];
    const float* p2 = (const float*)d_in[2];
    float* out = (float*)d_out;

    char* ws = (char*)d_ws;
    float* so_arr = (float*)ws;                    // 1,456,128 B
    float* xthr   = (float*)(ws + 1456128ull);     // 1,456,128 B

    static const float ANC[3][3][2] = {
        {{12, 16}, {19, 36}, {40, 28}},
        {{36, 75}, {76, 55}, {72, 146}},
        {{142, 110}, {192, 243}, {459, 401}},
    };
    static const int RED[3] = {8, 16, 32};
    static const int SS[3]  = {76, 38, 19};

    DecParams dp;
    for (int s = 0; s < 3; ++s)
        for (int a = 0; a < 3; ++a) {
            float Sf = (float)SS[s];
            dp.aw[s * 3 + a] = (ANC[s][a][0] / (float)RED[s]) / Sf;  // same f32 chain as ref
            dp.ah[s * 3 + a] = (ANC[s][a][1] / (float)RED[s]) / Sf;
        }

    decode_kernel<<<BATCH * 27, 256, 0, stream>>>(p0, p1, p2, so_arr, xthr);
    select_nms_kernel<<<BATCH * NCLS, 256, 0, stream>>>(p0, p1, p2, so_arr, xthr, dp, out);
}